// Round 6
// baseline (442.234 us; speedup 1.0000x reference)
//
#include <hip/hip_runtime.h>

#define Bb 128
#define Tt 1024
#define Dd 512
#define Vv 128
#define Ll 128
#define EPSF 1e-7f
#define PADK 72
#define NEGF -1e30f

typedef float f4 __attribute__((ext_vector_type(4)));
typedef short s8 __attribute__((ext_vector_type(8)));
typedef float f32x4 __attribute__((ext_vector_type(4)));

__device__ inline unsigned int f2bf(float f) {
    unsigned int u = __float_as_uint(f);
    return (u + 0x7fffu + ((u >> 16) & 1u)) >> 16;  // RNE bf16 (no NaN inputs)
}

// logaddexp via hw v_exp_f32/v_log_f32 -- used only in the one-time readout.
__device__ inline float lae2(float x, float y) {
    float m = fmaxf(x, y);
    float d = fminf(x, y) - m;                       // <= 0 (0 when both NEG)
    return m + __logf(1.f + __expf(d));
}

// wave-wide shift-up-by-1 (lane i reads lane i-1, lane0 -> 0): DPP wave_shr:1
__device__ inline float dpp_shr1(float v) {
    return __int_as_float(__builtin_amdgcn_update_dpp(
        0, __float_as_int(v), 0x138, 0xf, 0xf, false));
}
__device__ inline int dpp_shr1_i(int v) {
    return __builtin_amdgcn_update_dpp(0, v, 0x138, 0xf, 0xf, false);
}

// Prep: W [512,128] f32 -> Wt [v][k] bf16 (B^T layout for MFMA B-operand)
__global__ void wt_kernel(const float* __restrict__ W, unsigned short* __restrict__ Wt) {
    int idx = blockIdx.x * 256 + threadIdx.x;   // 65536
    int v = idx >> 9, k = idx & 511;
    Wt[idx] = (unsigned short)f2bf(W[k * Vv + v]);
}

// Fused GEMM (bf16 MFMA) + bias + softmax. Output TRANSPOSED: LP_T[b][v][t].
// K-loop is register-staged double-buffered: tile k+1's global loads issue
// BEFORE tile k's MFMA (latency hides under compute), cvt+ds_write after,
// ONE barrier per K-step. f32->bf16 via v_cvt_pk_bf16_f32 (RNE, 1 inst per
// 2 floats vs ~12 for the bit-twiddle path).
__global__ __launch_bounds__(256) void gemm_softmax(
    const float* __restrict__ x, const unsigned short* __restrict__ Wt,
    const float* __restrict__ bias, float* __restrict__ LP)
{
    // staging: A dbuf 2x18432B + B dbuf 2x18432B = 73728B; epilogue aliases
    // the first 64KB as float[16384] logits/probs.
    __shared__ __align__(16) char smem[73728];
    __shared__ __align__(16) float invs[128];
    unsigned short* Al0 = (unsigned short*)smem;
    unsigned short* Al1 = (unsigned short*)(smem + 18432);
    unsigned short* Bl0 = (unsigned short*)(smem + 36864);
    unsigned short* Bl1 = (unsigned short*)(smem + 55296);
    float* lds = (float*)smem;

    const int tid = threadIdx.x;
    const int wave = tid >> 6, lane = tid & 63;
    const int lm = lane & 15, lq = lane >> 4;
    const int wm = (wave >> 1) << 6, wn = (wave & 1) << 6;
    const long row0 = (long)blockIdx.x << 7;

    f32x4 acc[4][4];
    #pragma unroll
    for (int i = 0; i < 4; i++)
        #pragma unroll
        for (int j = 0; j < 4; j++)
            acc[i][j] = (f32x4){0.f, 0.f, 0.f, 0.f};

    f4 ra[8], rb[4];

#define STAGE_REGS(K0) do {                                                 \
    int kb_ = (K0) << 6;                                                    \
    _Pragma("unroll")                                                       \
    for (int i = 0; i < 8; i++) {                                           \
        int idx = tid + (i << 8);                                           \
        int r = idx >> 4, c4 = idx & 15;                                    \
        ra[i] = *(const f4*)(x + (row0 + r) * Dd + kb_ + (c4 << 2));        \
    }                                                                       \
    _Pragma("unroll")                                                       \
    for (int i = 0; i < 4; i++) {                                           \
        int idx = tid + (i << 8);                                           \
        int vr = idx >> 3, c = idx & 7;                                     \
        rb[i] = *(const f4*)(Wt + vr * 512 + kb_ + (c << 3));               \
    } } while (0)

#define WRITE_LDS(AL, BL) do {                                              \
    _Pragma("unroll")                                                       \
    for (int i = 0; i < 8; i++) {                                           \
        int idx = tid + (i << 8);                                           \
        int r = idx >> 4, c4 = idx & 15;                                    \
        unsigned int lo_, hi_;                                              \
        asm("v_cvt_pk_bf16_f32 %0, %1, %2" : "=v"(lo_)                      \
            : "v"(ra[i].x), "v"(ra[i].y));                                  \
        asm("v_cvt_pk_bf16_f32 %0, %1, %2" : "=v"(hi_)                      \
            : "v"(ra[i].z), "v"(ra[i].w));                                  \
        unsigned long long q_ = (unsigned long long)lo_                     \
                              | ((unsigned long long)hi_ << 32);            \
        *(unsigned long long*)((AL) + r * PADK + (c4 << 2)) = q_;           \
    }                                                                       \
    _Pragma("unroll")                                                       \
    for (int i = 0; i < 4; i++) {                                           \
        int idx = tid + (i << 8);                                           \
        int vr = idx >> 3, c = idx & 7;                                     \
        *(f4*)((BL) + vr * PADK + (c << 3)) = rb[i];                        \
    } } while (0)

#define MFMA_TILE(AL, BL) do {                                              \
    _Pragma("unroll")                                                       \
    for (int kk = 0; kk < 64; kk += 32) {                                   \
        s8 afr[4], bfr[4];                                                  \
        _Pragma("unroll")                                                   \
        for (int mi = 0; mi < 4; mi++)                                      \
            afr[mi] = *(const s8*)((AL) + (wm + (mi << 4) + lm) * PADK      \
                                    + kk + (lq << 3));                      \
        _Pragma("unroll")                                                   \
        for (int ni = 0; ni < 4; ni++)                                      \
            bfr[ni] = *(const s8*)((BL) + (wn + (ni << 4) + lm) * PADK      \
                                    + kk + (lq << 3));                      \
        _Pragma("unroll")                                                   \
        for (int mi = 0; mi < 4; mi++)                                      \
            _Pragma("unroll")                                               \
            for (int ni = 0; ni < 4; ni++)                                  \
                acc[mi][ni] = __builtin_amdgcn_mfma_f32_16x16x32_bf16(      \
                    afr[mi], bfr[ni], acc[mi][ni], 0, 0, 0);                \
    } } while (0)

    STAGE_REGS(0);
    WRITE_LDS(Al0, Bl0);
    __syncthreads();
    #pragma unroll
    for (int s = 0; s < 4; s++) {
        STAGE_REGS(2 * s + 1);            // issue loads; waited in WRITE_LDS below
        MFMA_TILE(Al0, Bl0);              // tile 2s
        WRITE_LDS(Al1, Bl1);
        __syncthreads();
        if (s < 3) STAGE_REGS(2 * s + 2);
        MFMA_TILE(Al1, Bl1);              // tile 2s+1
        if (s < 3) {
            WRITE_LDS(Al0, Bl0);
            __syncthreads();
        }
    }
    __syncthreads();
    // write logits+bias to XOR-swizzled LDS: word(t,v) = t*128 +
    // ((v>>2 ^ (t>>2)&7)<<2) + (v&3)  (bijective per row)
    #pragma unroll
    for (int mi = 0; mi < 4; mi++) {
        #pragma unroll
        for (int ni = 0; ni < 4; ni++) {
            int col = wn + (ni << 4) + lm;
            float bv = bias[col];
            #pragma unroll
            for (int r = 0; r < 4; r++) {
                int row = wm + (mi << 4) + (lq << 2) + r;
                int word = (row << 7) + ((((col >> 2) ^ ((row >> 2) & 7)) & 31) << 2) + (col & 3);
                lds[word] = acc[mi][ni][r] + bv;
            }
        }
    }
    __syncthreads();
    // pass 1+2: paired per-row max/exp/sum -- thread (row = tid>>1, h = tid&1)
    // handles 16 chunks; pair combines via shfl_xor(1). All 256 threads busy.
    {
        const int row = tid >> 1, h = tid & 1;
        float m = -1e30f;
        #pragma unroll
        for (int cc = 0; cc < 16; cc++) {
            int word = (row << 7) + (((cc + (h << 4) + row) & 31) << 2);
            f4 v = *(const f4*)(lds + word);
            m = fmaxf(m, fmaxf(fmaxf(v.x, v.y), fmaxf(v.z, v.w)));
        }
        m = fmaxf(m, __shfl_xor(m, 1));
        float s = 0.f;
        #pragma unroll
        for (int cc = 0; cc < 16; cc++) {
            int word = (row << 7) + (((cc + (h << 4) + row) & 31) << 2);
            f4 v = *(f4*)(lds + word);
            v.x = __expf(v.x - m); v.y = __expf(v.y - m);
            v.z = __expf(v.z - m); v.w = __expf(v.w - m);
            s += v.x + v.y + v.z + v.w;
            *(f4*)(lds + word) = v;
        }
        s += __shfl_xor(s, 1);
        if (h == 0) invs[row] = 1.f / s;
    }
    __syncthreads();
    // pass 3: coalesced transposed store. thread -> (l = tid&31 -> t = 4l,
    // g = tid>>5 -> v = 16g + jj). Per instruction each half-wave writes one
    // v-row's contiguous 512 B. LDS column reads ~4-way via the XOR swizzle.
    {
        const int l = tid & 31, g = tid >> 5;
        const int bidx = blockIdx.x >> 3;           // example
        const int tbase = (blockIdx.x & 7) << 7;    // t-offset within example
        const f4 iv = *(const f4*)(invs + (l << 2));    // inv[4l .. 4l+3]
        #pragma unroll
        for (int jj = 0; jj < 16; jj++) {
            const int v = (g << 4) + jj;
            const int swz = ((v >> 2) ^ (l & 7)) << 2;  // (t>>2)&7 == l&7
            const int r0 = v & 3;
            f4 o;
            #pragma unroll
            for (int r = 0; r < 4; r++) {
                int t = (l << 2) + r;
                o[r] = fmaf(lds[(t << 7) + swz + r0], iv[r], EPSF);
            }
            *(f4*)(LP + ((long)bidx * Vv + v) * Tt + tbase + (l << 2)) = o;
        }
    }
#undef STAGE_REGS
#undef WRITE_LDS
#undef MFMA_TILE
}

// CTC forward DP, LINEAR domain with per-lane power-of-2 anchors.
// One wave per example; lane i owns states 4i..4i+3 as u_s ~= alpha_s / 2^anc.
// P is TRANSPOSED [b][v][t]: each lane reads 3 sequential streams, depth-2
// register pipeline (3 rotating buffer sets). Per step: 13 VALU ops -- one
// DPP feed, selects folded into FMAs via precomputed fprevA (= mA?fprev:0,
// refreshed each rescale) and mBf (= mB?1:0). Rescale every 4 steps;
// windows 0..15 carry dead-lane anchor adoption, 16..63 lean (all 257
// states provably live by t=255: s->s+1 always legal with p>=eps).
__global__ __launch_bounds__(64) void ctc_kernel(
    const float* __restrict__ PT, const int* __restrict__ targets,
    const int* __restrict__ tlen, float* __restrict__ out)
{
    const int b = blockIdx.x;
    const int lane = threadIdx.x;
    const float* baseP = PT + (long)b * Vv * Tt;

    const int tgt0 = targets[(b << 7) + (lane << 1)];
    const int tgt1 = targets[(b << 7) + (lane << 1) + 1];
    int tp = __shfl_up(tgt1, 1);
    if (lane == 0) tp = -1;
    const bool mA = (tgt0 != tp);      // skip allowed into s=4i+1
    const bool mB = (tgt1 != tgt0);    // skip allowed into s=4i+3
    const float mBf = mB ? 1.f : 0.f;

    const float* pB = baseP + 127 * Tt;
    const float* p0 = baseP + (long)tgt0 * Tt;
    const float* p1 = baseP + (long)tgt1 * Tt;

    // t = 0: only s=0 (blank) and s=1 (first label) reachable
    float u0 = (lane == 0) ? pB[0] : 0.f;
    float u1 = (lane == 0) ? p0[0] : 0.f;
    float u2 = 0.f, u3 = 0.f, u4 = 0.f;
    int anc = 0;             // per-lane anchor: alpha = u * 2^anc
    float fprev = 1.f;       // 2^(anc_{lane-1} - anc)
    float fprevA = mA ? 1.f : 0.f;

    // three rotating buffer sets, 4 f4 per stream each
    f4 Xb[4], Xs[4], Xt[4], Yb[4], Ys[4], Yt[4], Zb[4], Zs[4], Zt[4];

#define LOADW(BUF, W) do {                                                  \
    int tn_ = ((W) < 63 ? (W) : 63) << 4;                                   \
    _Pragma("unroll")                                                       \
    for (int q = 0; q < 4; q++) {                                           \
        BUF##b[q] = *(const f4*)(pB + tn_ + (q << 2));                      \
        BUF##s[q] = *(const f4*)(p0 + tn_ + (q << 2));                      \
        BUF##t[q] = *(const f4*)(p1 + tn_ + (q << 2));                      \
    } } while (0)

#define DOSTEP(BUF, i) do {                                                 \
    float lb = BUF##b[(i) >> 2][(i) & 3];                                   \
    float l0 = BUF##s[(i) >> 2][(i) & 3];                                   \
    float l1 = BUF##t[(i) >> 2][(i) & 3];                                   \
    float s_ = dpp_shr1(u3);                      /* lane0 -> 0 */          \
    float t01 = u0 + u1;                                                    \
    float n0 = fmaf(s_, fprev,  u0) * lb;                                   \
    float n1 = fmaf(s_, fprevA, t01) * l0;                                  \
    float n2 = (u1 + u2) * lb;                                              \
    float n3 = fmaf(u1, mBf, u2 + u3) * l1;                                 \
    float n4 = (u3 + u4) * lb;                                              \
    u0 = n0; u1 = n1; u2 = n2; u3 = n3; u4 = n4; } while (0)

#define RESCALE(ADOPT) do {                                                 \
    float umax = fmaxf(fmaxf(fmaxf(u0, u1), fmaxf(u2, u3)), u4);            \
    int e = (int)((__float_as_uint(umax) >> 23) & 0xffu) - 126;             \
    float sc = __uint_as_float((unsigned)(127 - e) << 23);   /* 2^-e */     \
    u0 *= sc; u1 *= sc; u2 *= sc; u3 *= sc; u4 *= sc;    /* dead: 0->0 */   \
    if (ADOPT) {                                                            \
        bool live = umax > 0.f;                                             \
        anc = live ? (anc + e) : anc;                                       \
        _Pragma("unroll")                                                   \
        for (int r_ = 0; r_ < 3; r_++) {                                    \
            int cp_ = dpp_shr1_i(anc);                                      \
            anc = live ? anc : cp_;                                         \
        }                                                                   \
    } else {                                                                \
        anc += e;                                                           \
    }                                                                       \
    int cp = dpp_shr1_i(anc);                                               \
    int d_ = cp - anc;                                                      \
    d_ = d_ > 96 ? 96 : d_;          /* cap: feed stays finite */           \
    fprev = (d_ < -126) ? 0.f                                               \
           : __uint_as_float((unsigned)((d_ + 127) << 23));                 \
    fprevA = mA ? fprev : 0.f; } while (0)

#define WINDOW(CUR, N2, W, ADOPT, ISTART) do {                              \
    LOADW(N2, (W) + 2);                                                     \
    _Pragma("unroll")                                                       \
    for (int i = ISTART; i < 16; i++) {                                     \
        DOSTEP(CUR, i);                                                     \
        if ((i & 3) == 3) RESCALE(ADOPT);                                   \
    } } while (0)

    LOADW(X, 0);
    LOADW(Y, 1);
    WINDOW(X, Z, 0, true, 1);                    // win0 (t=1..15), loads win2
    for (int g = 0; g < 5; g++) {                // w = 1..15, adoption phase
        int w = 1 + 3 * g;
        WINDOW(Y, X, w,     true, 0);
        WINDOW(Z, Y, w + 1, true, 0);
        WINDOW(X, Z, w + 2, true, 0);
    }
    for (int g = 0; g < 16; g++) {               // w = 16..63, lean phase
        int w = 16 + 3 * g;
        WINDOW(Y, X, w,     false, 0);
        WINDOW(Z, Y, w + 1, false, 0);
        WINDOW(X, Z, w + 2, false, 0);
    }

    // readout: convert lane states to log domain once, then exact lae2
    __shared__ float af[257];
    const float LN2 = 0.69314718056f;
    float fa = (float)anc;
    af[(lane << 2) + 0] = u0 > 0.f ? (fa + log2f(u0)) * LN2 : NEGF;
    af[(lane << 2) + 1] = u1 > 0.f ? (fa + log2f(u1)) * LN2 : NEGF;
    af[(lane << 2) + 2] = u2 > 0.f ? (fa + log2f(u2)) * LN2 : NEGF;
    af[(lane << 2) + 3] = u3 > 0.f ? (fa + log2f(u3)) * LN2 : NEGF;
    if (lane == 63) af[256] = u4 > 0.f ? (fa + log2f(u4)) * LN2 : NEGF;
    __syncthreads();
    if (lane == 0) {
        int len = tlen[b];
        float loss = -lae2(af[2 * len], af[2 * len - 1]);
        atomicAdd(out, loss);
    }
}

extern "C" void kernel_launch(void* const* d_in, const int* in_sizes, int n_in,
                              void* d_out, int out_size, void* d_ws, size_t ws_size,
                              hipStream_t stream) {
    const float* x       = (const float*)d_in[0];
    const float* W       = (const float*)d_in[1];
    const float* bias    = (const float*)d_in[2];
    const int*   targets = (const int*)d_in[3];
    const int*   tl      = (const int*)d_in[4];
    float* out = (float*)d_out;

    float* LP = (float*)d_ws;                                      // 64 MB transposed probs
    unsigned short* Wt = (unsigned short*)((char*)d_ws + (size_t)Bb * Tt * Vv * 4);

    (void)hipMemsetAsync(out, 0, sizeof(float), stream);
    wt_kernel<<<256, 256, 0, stream>>>(W, Wt);
    gemm_softmax<<<1024, 256, 0, stream>>>(x, Wt, bias, LP);
    ctc_kernel<<<Bb, 64, 0, stream>>>(LP, targets, tl, out);
}

// Round 7
// 430.468 us; speedup vs baseline: 1.0273x; 1.0273x over previous
//
#include <hip/hip_runtime.h>

#define Bb 128
#define Tt 1024
#define Dd 512
#define Vv 128
#define Ll 128
#define EPSF 1e-7f
#define NEGF -1e30f

typedef float f4 __attribute__((ext_vector_type(4)));
typedef short s8 __attribute__((ext_vector_type(8)));
typedef unsigned int u32x4 __attribute__((ext_vector_type(4)));
typedef float f32x4 __attribute__((ext_vector_type(4)));

__device__ inline unsigned int f2bf(float f) {
    unsigned int u = __float_as_uint(f);
    return (u + 0x7fffu + ((u >> 16) & 1u)) >> 16;  // RNE bf16 (no NaN inputs)
}

// logaddexp via hw v_exp_f32/v_log_f32 -- used only in the one-time readout.
__device__ inline float lae2(float x, float y) {
    float m = fmaxf(x, y);
    float d = fminf(x, y) - m;                       // <= 0 (0 when both NEG)
    return m + __logf(1.f + __expf(d));
}

// wave-wide shift-up-by-1 (lane i reads lane i-1, lane0 -> 0): DPP wave_shr:1
__device__ inline float dpp_shr1(float v) {
    return __int_as_float(__builtin_amdgcn_update_dpp(
        0, __float_as_int(v), 0x138, 0xf, 0xf, false));
}
__device__ inline int dpp_shr1_i(int v) {
    return __builtin_amdgcn_update_dpp(0, v, 0x138, 0xf, 0xf, false);
}

// Prep: W [512,128] f32 -> Wt [v][k] bf16 (B^T layout for MFMA B-operand)
__global__ void wt_kernel(const float* __restrict__ W, unsigned short* __restrict__ Wt) {
    int idx = blockIdx.x * 256 + threadIdx.x;   // 65536
    int v = idx >> 9, k = idx & 511;
    Wt[idx] = (unsigned short)f2bf(W[k * Vv + v]);
}

// Fused GEMM (bf16 MFMA) + bias + softmax. Output TRANSPOSED: LP_T[b][v][t].
// Deep-pipeline staging (m97/m201 pattern): A-tile f32 via global_load_lds
// width-16 with pre-XOR-swizzled SOURCE addresses (linear LDS dest as HW
// requires; chunk c stored at p = c ^ (r&15) so frag ds_read_b128 is
// bank-spread). Counted s_waitcnt vmcnt(16) + raw s_barrier per K-step --
// stage(t+1) and B(t+1) stay in flight across the barrier (2 blocks/CU x
// 32KB in flight saturates HBM). B loads bf16 direct from L2-resident Wt
// to registers (no LDS, no cvt); A converts at read time via cvt_pk (RNE).
__global__ __launch_bounds__(256) void gemm_softmax(
    const float* __restrict__ x, const unsigned short* __restrict__ Wt,
    const float* __restrict__ bias, float* __restrict__ LP)
{
    __shared__ __align__(16) float Abuf[2][8192];   // 2 x 32 KB f32 A-tiles
    __shared__ __align__(16) float invs[128];
    float* lds = &Abuf[0][0];                       // epilogue alias: 64 KB logits

    const int tid = threadIdx.x;
    const int wave = tid >> 6, lane = tid & 63;
    const int lm = lane & 15, lq = lane >> 4;
    const int wm = (wave >> 1) << 6, wn = (wave & 1) << 6;
    const long row0 = (long)blockIdx.x << 7;

    f32x4 acc[4][4];
    #pragma unroll
    for (int i = 0; i < 4; i++)
        #pragma unroll
        for (int j = 0; j < 4; j++)
            acc[i][j] = (f32x4){0.f, 0.f, 0.f, 0.f};

    s8 breg[2][2][4];   // [buf][kk-half][ni] -- all indices compile-time after unroll

// stage K-step K0 into BUF: dest elem d = wave*2048 + i*256 + lane*4 (linear),
// row r = d>>6, dest chunk p = lane&15, source chunk c = p ^ (r&15).
#define STAGE(BUF, K0) do {                                                 \
    _Pragma("unroll")                                                       \
    for (int i = 0; i < 8; i++) {                                           \
        int r_ = (wave << 5) + (i << 2) + (lane >> 4);                      \
        int c_ = (lane & 15) ^ (r_ & 15);                                   \
        const float* gsrc = x + (row0 + r_) * Dd + (K0) + (c_ << 2);        \
        float* ldst = &(BUF)[(wave << 11) + (i << 8)];                      \
        __builtin_amdgcn_global_load_lds(                                   \
            (const __attribute__((address_space(1))) unsigned int*)gsrc,    \
            (__attribute__((address_space(3))) unsigned int*)ldst,          \
            16, 0, 0);                                                      \
    } } while (0)

#define LOADB(TB, K0) do {                                                  \
    _Pragma("unroll")                                                       \
    for (int kx = 0; kx < 2; kx++)                                          \
        _Pragma("unroll")                                                   \
        for (int ni = 0; ni < 4; ni++)                                      \
            breg[TB][kx][ni] = *(const s8*)(Wt + (wn + (ni << 4) + lm) * 512 \
                                            + (K0) + (kx << 5) + (lq << 3)); \
    } while (0)

#define COMPUTE(BUF, TB) do {                                               \
    _Pragma("unroll")                                                       \
    for (int kx = 0; kx < 2; kx++) {                                        \
        s8 afr[4];                                                          \
        _Pragma("unroll")                                                   \
        for (int mi = 0; mi < 4; mi++) {                                    \
            int r_ = wm + (mi << 4) + lm;                                   \
            int c0_ = (kx << 3) + (lq << 1);                                \
            f4 lo = *(const f4*)&(BUF)[(r_ << 6) + ((c0_ ^ (r_ & 15)) << 2)]; \
            f4 hi = *(const f4*)&(BUF)[(r_ << 6) + (((c0_ + 1) ^ (r_ & 15)) << 2)]; \
            unsigned int w0_, w1_, w2_, w3_;                                \
            asm("v_cvt_pk_bf16_f32 %0, %1, %2" : "=v"(w0_) : "v"(lo.x), "v"(lo.y)); \
            asm("v_cvt_pk_bf16_f32 %0, %1, %2" : "=v"(w1_) : "v"(lo.z), "v"(lo.w)); \
            asm("v_cvt_pk_bf16_f32 %0, %1, %2" : "=v"(w2_) : "v"(hi.x), "v"(hi.y)); \
            asm("v_cvt_pk_bf16_f32 %0, %1, %2" : "=v"(w3_) : "v"(hi.z), "v"(hi.w)); \
            union { u32x4 u; s8 s; } cv_;                                   \
            cv_.u = (u32x4){w0_, w1_, w2_, w3_};                            \
            afr[mi] = cv_.s;                                                \
        }                                                                   \
        _Pragma("unroll")                                                   \
        for (int mi = 0; mi < 4; mi++)                                      \
            _Pragma("unroll")                                               \
            for (int ni = 0; ni < 4; ni++)                                  \
                acc[mi][ni] = __builtin_amdgcn_mfma_f32_16x16x32_bf16(      \
                    afr[mi], breg[TB][kx][ni], acc[mi][ni], 0, 0, 0);       \
    } } while (0)

    STAGE(Abuf[0], 0);
    LOADB(0, 0);
    asm volatile("s_waitcnt vmcnt(0)");
    __builtin_amdgcn_sched_barrier(0);
    __builtin_amdgcn_s_barrier();

    #pragma unroll
    for (int t = 0; t < 8; t++) {
        if (t < 7) {
            STAGE(Abuf[(t + 1) & 1], (t + 1) << 6);
            LOADB((t + 1) & 1, (t + 1) << 6);
            asm volatile("s_waitcnt vmcnt(16)");   // A(t),B(t) done; t+1 in flight
        } else {
            asm volatile("s_waitcnt vmcnt(0)");
        }
        __builtin_amdgcn_sched_barrier(0);
        COMPUTE(Abuf[t & 1], t & 1);
        __builtin_amdgcn_s_barrier();              // buf reuse fence (no drain)
    }
#undef STAGE
#undef LOADB
#undef COMPUTE

    // ---- epilogue (proven R5/R6) ----
    // write logits+bias to XOR-swizzled LDS: word(t,v) = t*128 +
    // ((v>>2 ^ (t>>2)&7)<<2) + (v&3)  (bijective per row)
    #pragma unroll
    for (int mi = 0; mi < 4; mi++) {
        #pragma unroll
        for (int ni = 0; ni < 4; ni++) {
            int col = wn + (ni << 4) + lm;
            float bv = bias[col];
            #pragma unroll
            for (int r = 0; r < 4; r++) {
                int row = wm + (mi << 4) + (lq << 2) + r;
                int word = (row << 7) + ((((col >> 2) ^ ((row >> 2) & 7)) & 31) << 2) + (col & 3);
                lds[word] = acc[mi][ni][r] + bv;
            }
        }
    }
    __syncthreads();
    // paired per-row max/exp/sum -- thread (row = tid>>1, h = tid&1)
    {
        const int row = tid >> 1, h = tid & 1;
        float m = -1e30f;
        #pragma unroll
        for (int cc = 0; cc < 16; cc++) {
            int word = (row << 7) + (((cc + (h << 4) + row) & 31) << 2);
            f4 v = *(const f4*)(lds + word);
            m = fmaxf(m, fmaxf(fmaxf(v.x, v.y), fmaxf(v.z, v.w)));
        }
        m = fmaxf(m, __shfl_xor(m, 1));
        float s = 0.f;
        #pragma unroll
        for (int cc = 0; cc < 16; cc++) {
            int word = (row << 7) + (((cc + (h << 4) + row) & 31) << 2);
            f4 v = *(f4*)(lds + word);
            v.x = __expf(v.x - m); v.y = __expf(v.y - m);
            v.z = __expf(v.z - m); v.w = __expf(v.w - m);
            s += v.x + v.y + v.z + v.w;
            *(f4*)(lds + word) = v;
        }
        s += __shfl_xor(s, 1);
        if (h == 0) invs[row] = 1.f / s;
    }
    __syncthreads();
    // coalesced transposed store: thread (l = tid&31 -> t = 4l, g = tid>>5);
    // each half-wave writes one v-row's contiguous 512 B.
    {
        const int l = tid & 31, g = tid >> 5;
        const int bidx = blockIdx.x >> 3;           // example
        const int tbase = (blockIdx.x & 7) << 7;    // t-offset within example
        const f4 iv = *(const f4*)(invs + (l << 2));    // inv[4l .. 4l+3]
        #pragma unroll
        for (int jj = 0; jj < 16; jj++) {
            const int v = (g << 4) + jj;
            const int swz = ((v >> 2) ^ (l & 7)) << 2;  // (t>>2)&7 == l&7
            const int r0 = v & 3;
            f4 o;
            #pragma unroll
            for (int r = 0; r < 4; r++) {
                int t = (l << 2) + r;
                o[r] = fmaf(lds[(t << 7) + swz + r0], iv[r], EPSF);
            }
            *(f4*)(LP + ((long)bidx * Vv + v) * Tt + tbase + (l << 2)) = o;
        }
    }
}

// CTC forward DP, LINEAR domain with per-lane power-of-2 anchors.
// One wave per example; lane i owns states 4i..4i+3 as u_s ~= alpha_s / 2^anc.
// P is TRANSPOSED [b][v][t]: each lane reads 3 sequential streams, depth-2
// register pipeline (3 rotating buffer sets). Per step: 13 VALU ops -- one
// DPP feed, selects folded into FMAs via precomputed fprevA (= mA?fprev:0,
// refreshed each rescale) and mBf (= mB?1:0). Rescale every 4 steps;
// windows 0..15 carry dead-lane anchor adoption, 16..63 lean (all 257
// states provably live by t=255: s->s+1 always legal with p>=eps).
__global__ __launch_bounds__(64) void ctc_kernel(
    const float* __restrict__ PT, const int* __restrict__ targets,
    const int* __restrict__ tlen, float* __restrict__ out)
{
    const int b = blockIdx.x;
    const int lane = threadIdx.x;
    const float* baseP = PT + (long)b * Vv * Tt;

    const int tgt0 = targets[(b << 7) + (lane << 1)];
    const int tgt1 = targets[(b << 7) + (lane << 1) + 1];
    int tp = __shfl_up(tgt1, 1);
    if (lane == 0) tp = -1;
    const bool mA = (tgt0 != tp);      // skip allowed into s=4i+1
    const bool mB = (tgt1 != tgt0);    // skip allowed into s=4i+3
    const float mBf = mB ? 1.f : 0.f;

    const float* pB = baseP + 127 * Tt;
    const float* p0 = baseP + (long)tgt0 * Tt;
    const float* p1 = baseP + (long)tgt1 * Tt;

    // t = 0: only s=0 (blank) and s=1 (first label) reachable
    float u0 = (lane == 0) ? pB[0] : 0.f;
    float u1 = (lane == 0) ? p0[0] : 0.f;
    float u2 = 0.f, u3 = 0.f, u4 = 0.f;
    int anc = 0;             // per-lane anchor: alpha = u * 2^anc
    float fprev = 1.f;       // 2^(anc_{lane-1} - anc)
    float fprevA = mA ? 1.f : 0.f;

    // three rotating buffer sets, 4 f4 per stream each
    f4 Xb[4], Xs[4], Xt[4], Yb[4], Ys[4], Yt[4], Zb[4], Zs[4], Zt[4];

#define LOADW(BUF, W) do {                                                  \
    int tn_ = ((W) < 63 ? (W) : 63) << 4;                                   \
    _Pragma("unroll")                                                       \
    for (int q = 0; q < 4; q++) {                                           \
        BUF##b[q] = *(const f4*)(pB + tn_ + (q << 2));                      \
        BUF##s[q] = *(const f4*)(p0 + tn_ + (q << 2));                      \
        BUF##t[q] = *(const f4*)(p1 + tn_ + (q << 2));                      \
    } } while (0)

#define DOSTEP(BUF, i) do {                                                 \
    float lb = BUF##b[(i) >> 2][(i) & 3];                                   \
    float l0 = BUF##s[(i) >> 2][(i) & 3];                                   \
    float l1 = BUF##t[(i) >> 2][(i) & 3];                                   \
    float s_ = dpp_shr1(u3);                      /* lane0 -> 0 */          \
    float t01 = u0 + u1;                                                    \
    float n0 = fmaf(s_, fprev,  u0) * lb;                                   \
    float n1 = fmaf(s_, fprevA, t01) * l0;                                  \
    float n2 = (u1 + u2) * lb;                                              \
    float n3 = fmaf(u1, mBf, u2 + u3) * l1;                                 \
    float n4 = (u3 + u4) * lb;                                              \
    u0 = n0; u1 = n1; u2 = n2; u3 = n3; u4 = n4; } while (0)

#define RESCALE(ADOPT) do {                                                 \
    float umax = fmaxf(fmaxf(fmaxf(u0, u1), fmaxf(u2, u3)), u4);            \
    int e = (int)((__float_as_uint(umax) >> 23) & 0xffu) - 126;             \
    float sc = __uint_as_float((unsigned)(127 - e) << 23);   /* 2^-e */     \
    u0 *= sc; u1 *= sc; u2 *= sc; u3 *= sc; u4 *= sc;    /* dead: 0->0 */   \
    if (ADOPT) {                                                            \
        bool live = umax > 0.f;                                             \
        anc = live ? (anc + e) : anc;                                       \
        _Pragma("unroll")                                                   \
        for (int r_ = 0; r_ < 3; r_++) {                                    \
            int cp_ = dpp_shr1_i(anc);                                      \
            anc = live ? anc : cp_;                                         \
        }                                                                   \
    } else {                                                                \
        anc += e;                                                           \
    }                                                                       \
    int cp = dpp_shr1_i(anc);                                               \
    int d_ = cp - anc;                                                      \
    d_ = d_ > 96 ? 96 : d_;          /* cap: feed stays finite */           \
    fprev = (d_ < -126) ? 0.f                                               \
           : __uint_as_float((unsigned)((d_ + 127) << 23));                 \
    fprevA = mA ? fprev : 0.f; } while (0)

#define WINDOW(CUR, N2, W, ADOPT, ISTART) do {                              \
    LOADW(N2, (W) + 2);                                                     \
    _Pragma("unroll")                                                       \
    for (int i = ISTART; i < 16; i++) {                                     \
        DOSTEP(CUR, i);                                                     \
        if ((i & 3) == 3) RESCALE(ADOPT);                                   \
    } } while (0)

    LOADW(X, 0);
    LOADW(Y, 1);
    WINDOW(X, Z, 0, true, 1);                    // win0 (t=1..15), loads win2
    for (int g = 0; g < 5; g++) {                // w = 1..15, adoption phase
        int w = 1 + 3 * g;
        WINDOW(Y, X, w,     true, 0);
        WINDOW(Z, Y, w + 1, true, 0);
        WINDOW(X, Z, w + 2, true, 0);
    }
    for (int g = 0; g < 16; g++) {               // w = 16..63, lean phase
        int w = 16 + 3 * g;
        WINDOW(Y, X, w,     false, 0);
        WINDOW(Z, Y, w + 1, false, 0);
        WINDOW(X, Z, w + 2, false, 0);
    }

    // readout: convert lane states to log domain once, then exact lae2
    __shared__ float af[257];
    const float LN2 = 0.69314718056f;
    float fa = (float)anc;
    af[(lane << 2) + 0] = u0 > 0.f ? (fa + log2f(u0)) * LN2 : NEGF;
    af[(lane << 2) + 1] = u1 > 0.f ? (fa + log2f(u1)) * LN2 : NEGF;
    af[(lane << 2) + 2] = u2 > 0.f ? (fa + log2f(u2)) * LN2 : NEGF;
    af[(lane << 2) + 3] = u3 > 0.f ? (fa + log2f(u3)) * LN2 : NEGF;
    if (lane == 63) af[256] = u4 > 0.f ? (fa + log2f(u4)) * LN2 : NEGF;
    __syncthreads();
    if (lane == 0) {
        int len = tlen[b];
        float loss = -lae2(af[2 * len], af[2 * len - 1]);
        atomicAdd(out, loss);
    }
}

extern "C" void kernel_launch(void* const* d_in, const int* in_sizes, int n_in,
                              void* d_out, int out_size, void* d_ws, size_t ws_size,
                              hipStream_t stream) {
    const float* x       = (const float*)d_in[0];
    const float* W       = (const float*)d_in[1];
    const float* bias    = (const float*)d_in[2];
    const int*   targets = (const int*)d_in[3];
    const int*   tl      = (const int*)d_in[4];
    float* out = (float*)d_out;

    float* LP = (float*)d_ws;                                      // 64 MB transposed probs
    unsigned short* Wt = (unsigned short*)((char*)d_ws + (size_t)Bb * Tt * Vv * 4);

    (void)hipMemsetAsync(out, 0, sizeof(float), stream);
    wt_kernel<<<256, 256, 0, stream>>>(W, Wt);
    gemm_softmax<<<1024, 256, 0, stream>>>(x, Wt, bias, LP);
    ctc_kernel<<<Bb, 64, 0, stream>>>(LP, targets, tl, out);
}